// Round 2
// baseline (205.875 us; speedup 1.0000x reference)
//
#include <hip/hip_runtime.h>

#define S 48
#define D 4
#define PADC 2
#define P 52
#define SITES (S * S * S)        // 110592
#define PADVOL (P * P * P)       // 140608
#define N_IN 2048
#define H1 1024
#define H2 128
#define OUTN 10

__global__ void scatter_k(const float* __restrict__ vin,
                          const int* __restrict__ idx,
                          float* __restrict__ nm) {
    int t = blockIdx.x * blockDim.x + threadIdx.x;
    if (t < N_IN) {
        int x = idx[t * 3 + 0] + PADC;
        int y = idx[t * 3 + 1] + PADC;
        int z = idx[t * 3 + 2] + PADC;
        atomicAdd(&nm[(x * P + y) * P + z], vin[t]);
    }
}

__global__ __launch_bounds__(256) void step_k(const float* __restrict__ src,
                                              const float* __restrict__ syn,
                                              float* __restrict__ dst) {
    int s = blockIdx.x * 256 + threadIdx.x;   // grid sized exactly SITES/256
    int z = s % S;
    int q = s / S;
    int y = q % S;
    int x = q / S;
    const float4* sv = (const float4*)(syn + (size_t)s * 64);
    float acc = 0.0f;
#pragma unroll
    for (int a = 0; a < D; a++) {
#pragma unroll
        for (int b = 0; b < D; b++) {
            const float* row = src + ((x + a) * P + (y + b)) * P + z;
            float4 w = sv[a * D + b];
            acc += w.x * row[0] + w.y * row[1] + w.z * row[2] + w.w * row[3];
        }
    }
    acc = fmaxf(acc, 0.0f) * 0.9f;
    dst[((x + PADC) * P + (y + PADC)) * P + (z + PADC)] = acc;
}

// Layer-1 GEMV: x[110592] @ W1[110592,1024] -> per-chunk partials.
// Deterministic order-preserving compaction of nonzero rows (ballot/popcount)
// into LDS, then a BRANCH-FREE pipelined inner loop of float4 loads.
// Zero-row skip is exact (skipped terms contribute 0).
template <int RP>
__global__ __launch_bounds__(256) void gemv1_k(const float* __restrict__ nmfin,
                                               const float* __restrict__ W1,
                                               float* __restrict__ partial) {
    __shared__ float vals[RP];
    __shared__ int   rows[RP];
    __shared__ int   wtot[RP / 64];
    int blk = blockIdx.x;
    int t = threadIdx.x;
    int i0 = blk * RP;

    float v = 0.0f;
    bool nz = false;
    int pre = 0, wid = 0;
    if (t < RP) {                      // wave-uniform (RP multiple of 64)
        int i = i0 + t;
        int z = i % S;
        int q = i / S;
        int y = q % S;
        int x = q / S;
        v = nmfin[((x + PADC) * P + (y + PADC)) * P + (z + PADC)];
        nz = (v != 0.0f);
        unsigned long long mask = __ballot(nz);
        int lane = t & 63;
        wid = t >> 6;
        pre = __popcll(mask & ((1ull << lane) - 1ull));
        if (lane == 0) wtot[wid] = __popcll(mask);
    }
    __syncthreads();
    int nnz = 0;
#pragma unroll
    for (int w = 0; w < RP / 64; w++) nnz += wtot[w];
    if (nz) {
        int off = pre;
        for (int w = 0; w < wid; w++) off += wtot[w];
        rows[off] = t;
        vals[off] = v;
    }
    __syncthreads();

    const float4* W4 = (const float4*)W1;
    float4 a0 = {0.f, 0.f, 0.f, 0.f};
    float4 a1 = {0.f, 0.f, 0.f, 0.f};
    int i = 0;
#pragma unroll 2
    for (; i + 2 <= nnz; i += 2) {
        float x0 = vals[i], x1 = vals[i + 1];
        float4 w0 = W4[(size_t)(i0 + rows[i]) * (H1 / 4) + t];
        float4 w1 = W4[(size_t)(i0 + rows[i + 1]) * (H1 / 4) + t];
        a0.x += x0 * w0.x; a0.y += x0 * w0.y; a0.z += x0 * w0.z; a0.w += x0 * w0.w;
        a1.x += x1 * w1.x; a1.y += x1 * w1.y; a1.z += x1 * w1.z; a1.w += x1 * w1.w;
    }
    if (i < nnz) {
        float x0 = vals[i];
        float4 w0 = W4[(size_t)(i0 + rows[i]) * (H1 / 4) + t];
        a0.x += x0 * w0.x; a0.y += x0 * w0.y; a0.z += x0 * w0.z; a0.w += x0 * w0.w;
    }
    float4 acc = {a0.x + a1.x, a0.y + a1.y, a0.z + a1.z, a0.w + a1.w};
    ((float4*)(partial + (size_t)blk * H1))[t] = acc;
}

__global__ __launch_bounds__(256) void reduce1_k(const float* __restrict__ partial,
                                                 const float* __restrict__ b1,
                                                 float* __restrict__ y1, int nch) {
    int j = blockIdx.x * 256 + threadIdx.x;   // 4 blocks x 256 = 1024
    float s = b1[j];
#pragma unroll 8
    for (int r = 0; r < nch; r++) s += partial[(size_t)r * H1 + j];
    y1[j] = fmaxf(s, 0.0f);
}

__global__ __launch_bounds__(128) void gemv2_k(const float* __restrict__ y1,
                                               const float* __restrict__ W2,
                                               float* __restrict__ partial2) {
    __shared__ float ys[128];
    int b = blockIdx.x;   // 8 blocks, 128 rows each
    int t = threadIdx.x;
    ys[t] = y1[b * 128 + t];
    __syncthreads();
    float acc = 0.0f;
#pragma unroll 8
    for (int i = 0; i < 128; i++)
        acc += ys[i] * W2[(size_t)(b * 128 + i) * H2 + t];
    partial2[b * H2 + t] = acc;
}

__global__ __launch_bounds__(128) void final_k(const float* __restrict__ partial2,
                                               const float* __restrict__ b2,
                                               const float* __restrict__ W3,
                                               const float* __restrict__ b3,
                                               float* __restrict__ out) {
    __shared__ float y2[H2];
    int t = threadIdx.x;
    float s = b2[t];
#pragma unroll
    for (int k = 0; k < 8; k++) s += partial2[k * H2 + t];
    y2[t] = fmaxf(s, 0.0f);
    __syncthreads();
    if (t < OUTN) {
        float o = b3[t];
#pragma unroll 8
        for (int i = 0; i < H2; i++) o += y2[i] * W3[i * OUTN + t];
        out[t] = o;
    }
}

extern "C" void kernel_launch(void* const* d_in, const int* in_sizes, int n_in,
                              void* d_out, int out_size, void* d_ws, size_t ws_size,
                              hipStream_t stream) {
    const float* vinput  = (const float*)d_in[1];
    const float* synapse = (const float*)d_in[2];
    const float* W1      = (const float*)d_in[3];
    const float* b1      = (const float*)d_in[4];
    const float* W2      = (const float*)d_in[5];
    const float* b2      = (const float*)d_in[6];
    const float* W3      = (const float*)d_in[7];
    const float* b3      = (const float*)d_in[8];
    const int* node_idx  = (const int*)d_in[9];

    // prefer 128-row chunks (864 blocks) for occupancy; fall back to 256 if ws is tight
    const size_t fixed = 2 * (size_t)PADVOL + H1 + H1 + 64;
    int rp = 128;
    size_t nch = SITES / 128;
    if ((fixed + nch * H1) * sizeof(float) > ws_size) { rp = 256; nch = SITES / 256; }

    float* ws = (float*)d_ws;
    float* nm0 = ws;                          // PADVOL
    float* nm1 = nm0 + PADVOL;                // PADVOL
    float* partial1 = nm1 + PADVOL;           // nch * 1024
    float* y1 = partial1 + nch * H1;          // 1024
    float* partial2 = y1 + H1;                // 1024
    float* out = (float*)d_out;

    // zero both nm buffers (pads must stay zero; scatter accumulates)
    hipMemsetAsync(nm0, 0, 2 * (size_t)PADVOL * sizeof(float), stream);

    scatter_k<<<N_IN / 256, 256, 0, stream>>>(vinput, node_idx, nm0);

    const float* src = nm0;
    float* dst = nm1;
    for (int r = 0; r < 5; r++) {
        step_k<<<SITES / 256, 256, 0, stream>>>(src, synapse, dst);
        float* tmp = (float*)src;
        src = dst;
        dst = tmp;
    }
    // final interior now lives in `src`

    if (rp == 128)
        gemv1_k<128><<<(int)nch, 256, 0, stream>>>(src, W1, partial1);
    else
        gemv1_k<256><<<(int)nch, 256, 0, stream>>>(src, W1, partial1);
    reduce1_k<<<H1 / 256, 256, 0, stream>>>(partial1, b1, y1, (int)nch);
    gemv2_k<<<8, 128, 0, stream>>>(y1, W2, partial2);
    final_k<<<1, 128, 0, stream>>>(partial2, b2, W3, b3, out);
}

// Round 3
// 126.944 us; speedup vs baseline: 1.6218x; 1.6218x over previous
//
#include <hip/hip_runtime.h>

#define S 48
#define D 4
#define PADC 2
#define P 52
#define SITES (S * S * S)        // 110592
#define PADVOL (P * P * P)       // 140608
#define N_IN 2048
#define H1 1024
#define H2 128
#define OUTN 10
#define RP 64                    // rows per gemv1 block
#define NCH (SITES / RP)         // 1728
#define RG 16                    // row-groups in reduce stage A
#define CHPG (NCH / RG)          // 108 chunks per group

__global__ void scatter_k(const float* __restrict__ vin,
                          const int* __restrict__ idx,
                          float* __restrict__ nm) {
    int t = blockIdx.x * blockDim.x + threadIdx.x;
    if (t < N_IN) {
        int x = idx[t * 3 + 0] + PADC;
        int y = idx[t * 3 + 1] + PADC;
        int z = idx[t * 3 + 2] + PADC;
        atomicAdd(&nm[(x * P + y) * P + z], vin[t]);
    }
}

__global__ __launch_bounds__(256) void step_k(const float* __restrict__ src,
                                              const float* __restrict__ syn,
                                              float* __restrict__ dst) {
    int s = blockIdx.x * 256 + threadIdx.x;   // grid sized exactly SITES/256
    int z = s % S;
    int q = s / S;
    int y = q % S;
    int x = q / S;
    const float4* sv = (const float4*)(syn + (size_t)s * 64);
    float acc = 0.0f;
#pragma unroll
    for (int a = 0; a < D; a++) {
#pragma unroll
        for (int b = 0; b < D; b++) {
            const float* row = src + ((x + a) * P + (y + b)) * P + z;
            float4 w = sv[a * D + b];
            acc += w.x * row[0] + w.y * row[1] + w.z * row[2] + w.w * row[3];
        }
    }
    acc = fmaxf(acc, 0.0f) * 0.9f;
    dst[((x + PADC) * P + (y + PADC)) * P + (z + PADC)] = acc;
}

// Layer-1 GEMV with wave-uniform bitmask row skip.
// Block = 64 rows x 1024 cols. Every wave's lane l reads row l -> identical
// ballot mask in SGPRs. Scalar bit-loop (ctz / clear-lowest) drives pure
// base+i*4KB addressing; only the broadcast multiplier comes from LDS.
__global__ __launch_bounds__(256) void gemv1_k(const float* __restrict__ nmfin,
                                               const float* __restrict__ W1,
                                               float* __restrict__ partial) {
    __shared__ float xs[RP];
    int t = threadIdx.x;
    int lane = t & 63;
    int i0 = blockIdx.x * RP;

    // every wave reads the same 64 row values (L1 broadcast)
    int i = i0 + lane;
    int z = i % S;
    int q = i / S;
    int y = q % S;
    int x = q / S;
    float v = nmfin[((x + PADC) * P + (y + PADC)) * P + (z + PADC)];
    unsigned long long mask = __ballot(v != 0.0f);
    if (t < RP) xs[t] = v;       // wave 0 exactly
    __syncthreads();

    const float4* W4 = (const float4*)W1;
    size_t base = (size_t)i0 * (H1 / 4) + t;
    float4 a0 = {0.f, 0.f, 0.f, 0.f};
    float4 a1 = {0.f, 0.f, 0.f, 0.f};
    while (mask) {
        int r0 = (int)__builtin_ctzll(mask);
        mask &= mask - 1;
        if (mask) {
            int r1 = (int)__builtin_ctzll(mask);
            mask &= mask - 1;
            float x0 = xs[r0], x1 = xs[r1];
            float4 w0 = W4[base + (size_t)r0 * (H1 / 4)];
            float4 w1 = W4[base + (size_t)r1 * (H1 / 4)];
            a0.x += x0 * w0.x; a0.y += x0 * w0.y; a0.z += x0 * w0.z; a0.w += x0 * w0.w;
            a1.x += x1 * w1.x; a1.y += x1 * w1.y; a1.z += x1 * w1.z; a1.w += x1 * w1.w;
        } else {
            float x0 = xs[r0];
            float4 w0 = W4[base + (size_t)r0 * (H1 / 4)];
            a0.x += x0 * w0.x; a0.y += x0 * w0.y; a0.z += x0 * w0.z; a0.w += x0 * w0.w;
        }
    }
    float4 acc = {a0.x + a1.x, a0.y + a1.y, a0.z + a1.z, a0.w + a1.w};
    ((float4*)(partial + (size_t)blockIdx.x * H1))[t] = acc;
}

// reduce stage A: 64 blocks; block (g,c): sum 108 chunks for 256 cols
__global__ __launch_bounds__(256) void reduceA_k(const float* __restrict__ partial,
                                                 float* __restrict__ redB) {
    int g = blockIdx.x >> 2;
    int c = (blockIdx.x & 3) * 256 + threadIdx.x;
    float s = 0.0f;
    int r0 = g * CHPG;
#pragma unroll 4
    for (int r = r0; r < r0 + CHPG; r++) s += partial[(size_t)r * H1 + c];
    redB[g * H1 + c] = s;
}

// reduce stage B: 4 blocks; bias + relu
__global__ __launch_bounds__(256) void reduceB_k(const float* __restrict__ redB,
                                                 const float* __restrict__ b1,
                                                 float* __restrict__ y1) {
    int j = blockIdx.x * 256 + threadIdx.x;
    float s = b1[j];
#pragma unroll
    for (int g = 0; g < RG; g++) s += redB[g * H1 + j];
    y1[j] = fmaxf(s, 0.0f);
}

__global__ __launch_bounds__(128) void gemv2_k(const float* __restrict__ y1,
                                               const float* __restrict__ W2,
                                               float* __restrict__ partial2) {
    __shared__ float ys[128];
    int b = blockIdx.x;   // 8 blocks, 128 rows each
    int t = threadIdx.x;
    ys[t] = y1[b * 128 + t];
    __syncthreads();
    float acc = 0.0f;
#pragma unroll 8
    for (int i = 0; i < 128; i++)
        acc += ys[i] * W2[(size_t)(b * 128 + i) * H2 + t];
    partial2[b * H2 + t] = acc;
}

__global__ __launch_bounds__(128) void final_k(const float* __restrict__ partial2,
                                               const float* __restrict__ b2,
                                               const float* __restrict__ W3,
                                               const float* __restrict__ b3,
                                               float* __restrict__ out) {
    __shared__ float y2[H2];
    int t = threadIdx.x;
    float s = b2[t];
#pragma unroll
    for (int k = 0; k < 8; k++) s += partial2[k * H2 + t];
    y2[t] = fmaxf(s, 0.0f);
    __syncthreads();
    if (t < OUTN) {
        float o = b3[t];
#pragma unroll 8
        for (int i = 0; i < H2; i++) o += y2[i] * W3[i * OUTN + t];
        out[t] = o;
    }
}

extern "C" void kernel_launch(void* const* d_in, const int* in_sizes, int n_in,
                              void* d_out, int out_size, void* d_ws, size_t ws_size,
                              hipStream_t stream) {
    const float* vinput  = (const float*)d_in[1];
    const float* synapse = (const float*)d_in[2];
    const float* W1      = (const float*)d_in[3];
    const float* b1      = (const float*)d_in[4];
    const float* W2      = (const float*)d_in[5];
    const float* b2      = (const float*)d_in[6];
    const float* W3      = (const float*)d_in[7];
    const float* b3      = (const float*)d_in[8];
    const int* node_idx  = (const int*)d_in[9];

    float* ws = (float*)d_ws;
    float* nm0 = ws;                          // PADVOL
    float* nm1 = nm0 + PADVOL;                // PADVOL
    float* partial1 = nm1 + PADVOL;           // NCH * 1024 = 1.7M floats
    float* redB = partial1 + (size_t)NCH * H1; // 16 * 1024
    float* y1 = redB + RG * H1;               // 1024
    float* partial2 = y1 + H1;                // 1024
    float* out = (float*)d_out;

    // zero both nm buffers (pads must stay zero; scatter accumulates)
    hipMemsetAsync(nm0, 0, 2 * (size_t)PADVOL * sizeof(float), stream);

    scatter_k<<<N_IN / 256, 256, 0, stream>>>(vinput, node_idx, nm0);

    const float* src = nm0;
    float* dst = nm1;
    for (int r = 0; r < 5; r++) {
        step_k<<<SITES / 256, 256, 0, stream>>>(src, synapse, dst);
        float* tmp = (float*)src;
        src = dst;
        dst = tmp;
    }
    // final interior now lives in `src`

    gemv1_k<<<NCH, 256, 0, stream>>>(src, W1, partial1);
    reduceA_k<<<RG * 4, 256, 0, stream>>>(partial1, redB);
    reduceB_k<<<H1 / 256, 256, 0, stream>>>(redB, b1, y1);
    gemv2_k<<<8, 128, 0, stream>>>(y1, W2, partial2);
    final_k<<<1, 128, 0, stream>>>(partial2, b2, W3, b3, out);
}

// Round 4
// 107.254 us; speedup vs baseline: 1.9195x; 1.1836x over previous
//
#include <hip/hip_runtime.h>

#define S 48
#define D 4
#define PADC 2
#define P 52
#define SITES (S * S * S)        // 110592
#define PADVOL (P * P * P)       // 140608
#define N_IN 2048
#define H1 1024
#define H2 128
#define OUTN 10
#define RP 64                    // rows per gemv1 block
#define NCH (SITES / RP)         // 1728
#define RG 16                    // row-groups in reduce stage A
#define CHPG (NCH / RG)          // 108 chunks per group
#define G2B 32                   // gemv2 blocks (rows of W2 per block = 32)

__global__ void scatter_k(const float* __restrict__ vin,
                          const int* __restrict__ idx,
                          float* __restrict__ nm) {
    int t = blockIdx.x * blockDim.x + threadIdx.x;
    if (t < N_IN) {
        int x = idx[t * 3 + 0] + PADC;
        int y = idx[t * 3 + 1] + PADC;
        int z = idx[t * 3 + 2] + PADC;
        atomicAdd(&nm[(x * P + y) * P + z], vin[t]);
    }
}

// 2 lanes per site: lane-pair halves split the a-dimension (2x32 MACs),
// combined with shfl_xor. 864 blocks -> 2x the waves of the 1-thread/site
// version for latency hiding.
__global__ __launch_bounds__(256) void step_k(const float* __restrict__ src,
                                              const float* __restrict__ syn,
                                              float* __restrict__ dst) {
    int tid = threadIdx.x;
    int half = tid & 1;
    int sl = tid >> 1;                        // 0..127
    int s = blockIdx.x * 128 + sl;
    int z = s % S;
    int q = s / S;
    int y = q % S;
    int x = q / S;
    const float4* sv = (const float4*)(syn + (size_t)s * 64) + half * 8;
    int a0 = half * 2;
    float acc = 0.0f;
#pragma unroll
    for (int a = 0; a < 2; a++) {
#pragma unroll
        for (int b = 0; b < D; b++) {
            const float* row = src + ((x + a0 + a) * P + (y + b)) * P + z;
            float4 w = sv[a * 4 + b];
            acc += w.x * row[0] + w.y * row[1] + w.z * row[2] + w.w * row[3];
        }
    }
    acc += __shfl_xor(acc, 1);
    if (half == 0) {
        acc = fmaxf(acc, 0.0f) * 0.9f;
        dst[((x + PADC) * P + (y + PADC)) * P + (z + PADC)] = acc;
    }
}

// Layer-1 GEMV with wave-uniform SGPR bitmask row skip (unchanged from R3).
__global__ __launch_bounds__(256) void gemv1_k(const float* __restrict__ nmfin,
                                               const float* __restrict__ W1,
                                               float* __restrict__ partial) {
    __shared__ float xs[RP];
    int t = threadIdx.x;
    int lane = t & 63;
    int i0 = blockIdx.x * RP;

    int i = i0 + lane;
    int z = i % S;
    int q = i / S;
    int y = q % S;
    int x = q / S;
    float v = nmfin[((x + PADC) * P + (y + PADC)) * P + (z + PADC)];
    unsigned long long mask = __ballot(v != 0.0f);
    if (t < RP) xs[t] = v;
    __syncthreads();

    const float4* W4 = (const float4*)W1;
    size_t base = (size_t)i0 * (H1 / 4) + t;
    float4 a0 = {0.f, 0.f, 0.f, 0.f};
    float4 a1 = {0.f, 0.f, 0.f, 0.f};
    while (mask) {
        int r0 = (int)__builtin_ctzll(mask);
        mask &= mask - 1;
        if (mask) {
            int r1 = (int)__builtin_ctzll(mask);
            mask &= mask - 1;
            float x0 = xs[r0], x1 = xs[r1];
            float4 w0 = W4[base + (size_t)r0 * (H1 / 4)];
            float4 w1 = W4[base + (size_t)r1 * (H1 / 4)];
            a0.x += x0 * w0.x; a0.y += x0 * w0.y; a0.z += x0 * w0.z; a0.w += x0 * w0.w;
            a1.x += x1 * w1.x; a1.y += x1 * w1.y; a1.z += x1 * w1.z; a1.w += x1 * w1.w;
        } else {
            float x0 = xs[r0];
            float4 w0 = W4[base + (size_t)r0 * (H1 / 4)];
            a0.x += x0 * w0.x; a0.y += x0 * w0.y; a0.z += x0 * w0.z; a0.w += x0 * w0.w;
        }
    }
    float4 acc = {a0.x + a1.x, a0.y + a1.y, a0.z + a1.z, a0.w + a1.w};
    ((float4*)(partial + (size_t)blockIdx.x * H1))[t] = acc;
}

// reduce stage A: 64 blocks; block (g,c): sum 108 chunks for 256 cols
__global__ __launch_bounds__(256) void reduceA_k(const float* __restrict__ partial,
                                                 float* __restrict__ redB) {
    int g = blockIdx.x >> 2;
    int c = (blockIdx.x & 3) * 256 + threadIdx.x;
    float s = 0.0f;
    int r0 = g * CHPG;
#pragma unroll 4
    for (int r = r0; r < r0 + CHPG; r++) s += partial[(size_t)r * H1 + c];
    redB[g * H1 + c] = s;
}

// gemv2 with fused layer-1 finish: block b needs only y1 rows [b*32, b*32+32).
// Each block: compute that y1 slice from redB (+bias,relu), then the partial
// GEMV over its 32 rows x 128 cols of W2.
__global__ __launch_bounds__(128) void gemv2_k(const float* __restrict__ redB,
                                               const float* __restrict__ b1,
                                               const float* __restrict__ W2,
                                               float* __restrict__ partial2) {
    __shared__ float ys[H1 / G2B];            // 32
    int b = blockIdx.x;
    int t = threadIdx.x;
    int r0 = b * (H1 / G2B);
    if (t < H1 / G2B) {
        int j = r0 + t;
        float s = b1[j];
#pragma unroll
        for (int g = 0; g < RG; g++) s += redB[g * H1 + j];
        ys[t] = fmaxf(s, 0.0f);
    }
    __syncthreads();
    float acc = 0.0f;
#pragma unroll
    for (int i = 0; i < H1 / G2B; i++)
        acc += ys[i] * W2[(size_t)(r0 + i) * H2 + t];
    partial2[b * H2 + t] = acc;
}

__global__ __launch_bounds__(128) void final_k(const float* __restrict__ partial2,
                                               const float* __restrict__ b2,
                                               const float* __restrict__ W3,
                                               const float* __restrict__ b3,
                                               float* __restrict__ out) {
    __shared__ float y2[H2];
    int t = threadIdx.x;
    float s = b2[t];
#pragma unroll
    for (int k = 0; k < G2B; k++) s += partial2[k * H2 + t];
    y2[t] = fmaxf(s, 0.0f);
    __syncthreads();
    if (t < OUTN) {
        float o = b3[t];
#pragma unroll 8
        for (int i = 0; i < H2; i++) o += y2[i] * W3[i * OUTN + t];
        out[t] = o;
    }
}

extern "C" void kernel_launch(void* const* d_in, const int* in_sizes, int n_in,
                              void* d_out, int out_size, void* d_ws, size_t ws_size,
                              hipStream_t stream) {
    const float* vinput  = (const float*)d_in[1];
    const float* synapse = (const float*)d_in[2];
    const float* W1      = (const float*)d_in[3];
    const float* b1      = (const float*)d_in[4];
    const float* W2      = (const float*)d_in[5];
    const float* b2      = (const float*)d_in[6];
    const float* W3      = (const float*)d_in[7];
    const float* b3      = (const float*)d_in[8];
    const int* node_idx  = (const int*)d_in[9];

    float* ws = (float*)d_ws;
    float* nm0 = ws;                           // PADVOL
    float* nm1 = nm0 + PADVOL;                 // PADVOL
    float* partial1 = nm1 + PADVOL;            // NCH * 1024
    float* redB = partial1 + (size_t)NCH * H1; // 16 * 1024
    float* partial2 = redB + RG * H1;          // G2B * 128
    float* out = (float*)d_out;

    hipMemsetAsync(nm0, 0, 2 * (size_t)PADVOL * sizeof(float), stream);

    scatter_k<<<N_IN / 256, 256, 0, stream>>>(vinput, node_idx, nm0);

    const float* src = nm0;
    float* dst = nm1;
    for (int r = 0; r < 5; r++) {
        step_k<<<SITES / 128, 256, 0, stream>>>(src, synapse, dst);
        float* tmp = (float*)src;
        src = dst;
        dst = tmp;
    }

    gemv1_k<<<NCH, 256, 0, stream>>>(src, W1, partial1);
    reduceA_k<<<RG * 4, 256, 0, stream>>>(partial1, redB);
    gemv2_k<<<G2B, 128, 0, stream>>>(redB, b1, W2, partial2);
    final_k<<<1, 128, 0, stream>>>(partial2, b2, W3, b3, out);
}

// Round 5
// 93.503 us; speedup vs baseline: 2.2018x; 1.1471x over previous
//
#include <hip/hip_runtime.h>

#define S 48
#define D 4
#define PADC 2
#define P 52
#define SITES (S * S * S)        // 110592
#define PADVOL (P * P * P)       // 140608
#define N_IN 2048
#define H1 1024
#define H2 128
#define OUTN 10
#define RP 64                    // rows per gemv1 block
#define NCH (SITES / RP)         // 1728
#define RG 16                    // row-groups in reduce stage A
#define CHPG (NCH / RG)          // 108 chunks per group
#define G2B 32                   // gemv2 blocks (rows of W2 per block = 32)

__global__ __launch_bounds__(256) void zero_k(float4* __restrict__ p, int n4) {
    int i = blockIdx.x * 256 + threadIdx.x;
    if (i < n4) p[i] = make_float4(0.f, 0.f, 0.f, 0.f);
}

__global__ void scatter_k(const float* __restrict__ vin,
                          const int* __restrict__ idx,
                          float* __restrict__ nm) {
    int t = blockIdx.x * blockDim.x + threadIdx.x;
    if (t < N_IN) {
        int x = idx[t * 3 + 0] + PADC;
        int y = idx[t * 3 + 1] + PADC;
        int z = idx[t * 3 + 2] + PADC;
        atomicAdd(&nm[(x * P + y) * P + z], vin[t]);
    }
}

// 4 lanes per site: lane-group of 4 splits the b-dimension (4x16 MACs),
// combined with two shfl_xor. 1728 blocks -> 6.75 waves/SIMD.
// Each lane's synapse read per a-step is a full contiguous 64B run.
__global__ __launch_bounds__(256) void step_k(const float* __restrict__ src,
                                              const float* __restrict__ syn,
                                              float* __restrict__ dst) {
    int tid = threadIdx.x;
    int q = tid & 3;                          // b-index
    int sl = tid >> 2;                        // 0..63
    int s = blockIdx.x * 64 + sl;
    int z = s % S;
    int t2 = s / S;
    int y = t2 % S;
    int x = t2 / S;
    const float4* sv = (const float4*)(syn + (size_t)s * 64);
    float acc = 0.0f;
#pragma unroll
    for (int a = 0; a < D; a++) {
        const float* row = src + ((x + a) * P + (y + q)) * P + z;
        float4 w = sv[a * 4 + q];
        acc += w.x * row[0] + w.y * row[1] + w.z * row[2] + w.w * row[3];
    }
    acc += __shfl_xor(acc, 1);
    acc += __shfl_xor(acc, 2);
    if (q == 0) {
        dst[((x + PADC) * P + (y + PADC)) * P + (z + PADC)] = fmaxf(acc, 0.0f) * 0.9f;
    }
}

// Layer-1 GEMV with wave-uniform SGPR bitmask row skip (unchanged, proven).
__global__ __launch_bounds__(256) void gemv1_k(const float* __restrict__ nmfin,
                                               const float* __restrict__ W1,
                                               float* __restrict__ partial) {
    __shared__ float xs[RP];
    int t = threadIdx.x;
    int lane = t & 63;
    int i0 = blockIdx.x * RP;

    int i = i0 + lane;
    int z = i % S;
    int q = i / S;
    int y = q % S;
    int x = q / S;
    float v = nmfin[((x + PADC) * P + (y + PADC)) * P + (z + PADC)];
    unsigned long long mask = __ballot(v != 0.0f);
    if (t < RP) xs[t] = v;
    __syncthreads();

    const float4* W4 = (const float4*)W1;
    size_t base = (size_t)i0 * (H1 / 4) + t;
    float4 a0 = {0.f, 0.f, 0.f, 0.f};
    float4 a1 = {0.f, 0.f, 0.f, 0.f};
    while (mask) {
        int r0 = (int)__builtin_ctzll(mask);
        mask &= mask - 1;
        if (mask) {
            int r1 = (int)__builtin_ctzll(mask);
            mask &= mask - 1;
            float x0 = xs[r0], x1 = xs[r1];
            float4 w0 = W4[base + (size_t)r0 * (H1 / 4)];
            float4 w1 = W4[base + (size_t)r1 * (H1 / 4)];
            a0.x += x0 * w0.x; a0.y += x0 * w0.y; a0.z += x0 * w0.z; a0.w += x0 * w0.w;
            a1.x += x1 * w1.x; a1.y += x1 * w1.y; a1.z += x1 * w1.z; a1.w += x1 * w1.w;
        } else {
            float x0 = xs[r0];
            float4 w0 = W4[base + (size_t)r0 * (H1 / 4)];
            a0.x += x0 * w0.x; a0.y += x0 * w0.y; a0.z += x0 * w0.z; a0.w += x0 * w0.w;
        }
    }
    float4 acc = {a0.x + a1.x, a0.y + a1.y, a0.z + a1.z, a0.w + a1.w};
    ((float4*)(partial + (size_t)blockIdx.x * H1))[t] = acc;
}

// reduce stage A: 64 blocks; block (g,c): sum 108 chunks for 256 cols
__global__ __launch_bounds__(256) void reduceA_k(const float* __restrict__ partial,
                                                 float* __restrict__ redB) {
    int g = blockIdx.x >> 2;
    int c = (blockIdx.x & 3) * 256 + threadIdx.x;
    float s = 0.0f;
    int r0 = g * CHPG;
#pragma unroll 4
    for (int r = r0; r < r0 + CHPG; r++) s += partial[(size_t)r * H1 + c];
    redB[g * H1 + c] = s;
}

// gemv2 with fused layer-1 finish: block b needs only y1 rows [b*32, b*32+32).
__global__ __launch_bounds__(128) void gemv2_k(const float* __restrict__ redB,
                                               const float* __restrict__ b1,
                                               const float* __restrict__ W2,
                                               float* __restrict__ partial2) {
    __shared__ float ys[H1 / G2B];            // 32
    int b = blockIdx.x;
    int t = threadIdx.x;
    int r0 = b * (H1 / G2B);
    if (t < H1 / G2B) {
        int j = r0 + t;
        float s = b1[j];
#pragma unroll
        for (int g = 0; g < RG; g++) s += redB[g * H1 + j];
        ys[t] = fmaxf(s, 0.0f);
    }
    __syncthreads();
    float acc = 0.0f;
#pragma unroll
    for (int i = 0; i < H1 / G2B; i++)
        acc += ys[i] * W2[(size_t)(r0 + i) * H2 + t];
    partial2[b * H2 + t] = acc;
}

__global__ __launch_bounds__(128) void final_k(const float* __restrict__ partial2,
                                               const float* __restrict__ b2,
                                               const float* __restrict__ W3,
                                               const float* __restrict__ b3,
                                               float* __restrict__ out) {
    __shared__ float y2[H2];
    int t = threadIdx.x;
    float s = b2[t];
#pragma unroll
    for (int k = 0; k < G2B; k++) s += partial2[k * H2 + t];
    y2[t] = fmaxf(s, 0.0f);
    __syncthreads();
    if (t < OUTN) {
        float o = b3[t];
#pragma unroll 8
        for (int i = 0; i < H2; i++) o += y2[i] * W3[i * OUTN + t];
        out[t] = o;
    }
}

extern "C" void kernel_launch(void* const* d_in, const int* in_sizes, int n_in,
                              void* d_out, int out_size, void* d_ws, size_t ws_size,
                              hipStream_t stream) {
    const float* vinput  = (const float*)d_in[1];
    const float* synapse = (const float*)d_in[2];
    const float* W1      = (const float*)d_in[3];
    const float* b1      = (const float*)d_in[4];
    const float* W2      = (const float*)d_in[5];
    const float* b2      = (const float*)d_in[6];
    const float* W3      = (const float*)d_in[7];
    const float* b3      = (const float*)d_in[8];
    const int* node_idx  = (const int*)d_in[9];

    float* ws = (float*)d_ws;
    float* nm0 = ws;                           // PADVOL
    float* nm1 = nm0 + PADVOL;                 // PADVOL
    float* partial1 = nm1 + PADVOL;            // NCH * 1024
    float* redB = partial1 + (size_t)NCH * H1; // 16 * 1024
    float* partial2 = redB + RG * H1;          // G2B * 128
    float* out = (float*)d_out;

    // zero both nm buffers (pads must stay zero; scatter accumulates)
    const int n4 = 2 * PADVOL / 4;             // 70304 float4s
    zero_k<<<(n4 + 255) / 256, 256, 0, stream>>>((float4*)nm0, n4);

    scatter_k<<<N_IN / 256, 256, 0, stream>>>(vinput, node_idx, nm0);

    const float* src = nm0;
    float* dst = nm1;
    for (int r = 0; r < 5; r++) {
        step_k<<<SITES / 64, 256, 0, stream>>>(src, synapse, dst);
        float* tmp = (float*)src;
        src = dst;
        dst = tmp;
    }

    gemv1_k<<<NCH, 256, 0, stream>>>(src, W1, partial1);
    reduceA_k<<<RG * 4, 256, 0, stream>>>(partial1, redB);
    gemv2_k<<<G2B, 128, 0, stream>>>(redB, b1, W2, partial2);
    final_k<<<1, 128, 0, stream>>>(partial2, b2, W3, b3, out);
}